// Round 2
// baseline (492.280 us; speedup 1.0000x reference)
//
#include <hip/hip_runtime.h>
#include <math.h>

#define NN_  (1024*1024)
#define NPTS (6*NN_)
#define E_   1023
#define VERT_ELEMS (NPTS*3)          // 18874368
#define FACE_ELEMS 37675044          // 2*6*1023*1023*3
#define FACE_VEC4  (FACE_ELEMS/4)    // 9418761

__device__ __forceinline__ float3 f3(float x, float y, float z){ float3 r; r.x=x;r.y=y;r.z=z; return r; }

__device__ __forceinline__ float3 loadv(const float* __restrict__ v, int f, int i, int j){
    int o = ((f << 20) + (i << 10) + j) * 3;
    return f3(v[o], v[o+1], v[o+2]);
}

__device__ __forceinline__ float3 tri_normal(float3 v0, float3 v1, float3 v2){
    float ax = v1.x - v0.x, ay = v1.y - v0.y, az = v1.z - v0.z;
    float bx = v2.x - v0.x, by = v2.y - v0.y, bz = v2.z - v0.z;
    float cx = ay*bz - az*by;
    float cy = az*bx - ax*bz;
    float cz = ax*by - ay*bx;
    float n = sqrtf(cx*cx + cy*cy + cz*cz);
    float inv = 1.0f / fmaxf(n, 1e-8f);
    return f3(cx*inv, cy*inv, cz*inv);
}

// ---------------- Kernel 1: vertices = sigmoid(avg_border(radii)) * angles ----
__global__ __launch_bounds__(256) void vert_kernel(const float* __restrict__ radii,
                                                   const float* __restrict__ angles,
                                                   float* __restrict__ vert) {
    int idx = blockIdx.x * blockDim.x + threadIdx.x;
    if (idx >= NPTS) return;
    int j = idx & 1023;
    int i = (idx >> 10) & 1023;
    int f = idx >> 20;

    float r = radii[idx];

    // border pairing: precedence j==0 > j==E > i==0 > i==E (last matching pair
    // in the reference's sequential .at().set() list wins; avg uses ORIGINAL r)
    int pf = -1, pi = 0, pj = 0;
    if (j == 0) {
        switch (f) {
            case 0: pf=5; pi=E_; pj=i;  break;
            case 1: pf=5; pi=0;  pj=i;  break;
            case 2: pf=5; pi=i;  pj=E_; break;
            case 3: pf=5; pi=i;  pj=0;  break;
            case 4: pf=3; pi=i;  pj=E_; break;
            case 5: pf=3; pi=i;  pj=0;  break;
        }
    } else if (j == E_) {
        switch (f) {
            case 0: pf=4; pi=E_; pj=i;  break;
            case 1: pf=4; pi=0;  pj=i;  break;
            case 2: pf=4; pi=i;  pj=E_; break;
            case 3: pf=4; pi=i;  pj=0;  break;
            case 4: pf=2; pi=i;  pj=E_; break;
            case 5: pf=2; pi=i;  pj=0;  break;
        }
    } else if (i == 0) {
        switch (f) {
            case 0: pf=3; pi=E_; pj=j;  break;
            case 1: pf=3; pi=0;  pj=j;  break;
            case 2: pf=1; pi=E_; pj=j;  break;
            case 3: pf=1; pi=0;  pj=j;  break;
            case 4: pf=1; pi=j;  pj=E_; break;
            case 5: pf=1; pi=j;  pj=0;  break;
        }
    } else if (i == E_) {
        switch (f) {
            case 0: pf=2; pi=E_; pj=j;  break;
            case 1: pf=2; pi=0;  pj=j;  break;
            case 2: pf=0; pi=E_; pj=j;  break;
            case 3: pf=0; pi=0;  pj=j;  break;
            case 4: pf=0; pi=j;  pj=E_; break;
            case 5: pf=0; pi=j;  pj=0;  break;
        }
    }
    if (pf >= 0) {
        float rp = radii[(pf << 20) + (pi << 10) + pj];
        r = 0.5f * (r + rp);
    }

    float s = 1.0f / (1.0f + __expf(-r));   // sigmoid

    int abase = (f * 3) << 20;
    int aoff  = (i << 10) + j;
    float ax = angles[abase + aoff];
    float ay = angles[abase + (1 << 20) + aoff];
    float az = angles[abase + (2 << 20) + aoff];

    int o = idx * 3;
    vert[o]   = s * ax;
    vert[o+1] = s * ay;
    vert[o+2] = s * az;
}

// ---------------- Kernel 2: faces int32 -> float32 copy ----------------------
__global__ __launch_bounds__(256) void faces_kernel(const int* __restrict__ fin,
                                                    float* __restrict__ fout) {
    int idx = blockIdx.x * blockDim.x + threadIdx.x;
    if (idx >= FACE_VEC4) return;
    int4 v = ((const int4* __restrict__)fin)[idx];
    float4 o;
    o.x = (float)v.x; o.y = (float)v.y; o.z = (float)v.z; o.w = (float)v.w;
    ((float4*)fout)[idx] = o;
}

// ---------------- Kernel 3: vertex normals via fixed 6-triangle gather -------
__global__ __launch_bounds__(256) void vn_kernel(const float* __restrict__ vert,
                                                 float* __restrict__ vn) {
    int idx = blockIdx.x * blockDim.x + threadIdx.x;
    if (idx >= NPTS) return;
    int j = idx & 1023;
    int i = (idx >> 10) & 1023;
    int f = idx >> 20;

    bool iN = (i > 0), iP = (i < E_), jN = (j > 0), jP = (j < E_);

    float3 c = loadv(vert, f, i, j);
    float3 pR = f3(0,0,0), pL = f3(0,0,0), pD = f3(0,0,0), pU = f3(0,0,0);
    float3 pDL = f3(0,0,0), pUR = f3(0,0,0);
    if (jP) pR  = loadv(vert, f, i,   j+1);
    if (jN) pL  = loadv(vert, f, i,   j-1);
    if (iP) pD  = loadv(vert, f, i+1, j);
    if (iN) pU  = loadv(vert, f, i-1, j);
    if (iP && jN) pDL = loadv(vert, f, i+1, j-1);
    if (iN && jP) pUR = loadv(vert, f, i-1, j+1);

    float sx = 0.f, sy = 0.f, sz = 0.f;
    // triangle list per mesh construction: t1=(a,b,c), t2=(c,b,d) of each cell
    if (iP && jP) { float3 n = tri_normal(c,   pR,  pD); sx+=n.x; sy+=n.y; sz+=n.z; } // t1 cell(i,j)
    if (iP && jN) { float3 n = tri_normal(pL,  c,   pDL); sx+=n.x; sy+=n.y; sz+=n.z; } // t1 cell(i,j-1)
    if (iN && jP) { float3 n = tri_normal(pU,  pUR, c);  sx+=n.x; sy+=n.y; sz+=n.z; } // t1 cell(i-1,j)
    if (iN && jP) { float3 n = tri_normal(c,   pUR, pR); sx+=n.x; sy+=n.y; sz+=n.z; } // t2 cell(i-1,j)
    if (iP && jN) { float3 n = tri_normal(pDL, c,   pD); sx+=n.x; sy+=n.y; sz+=n.z; } // t2 cell(i,j-1)
    if (iN && jN) { float3 n = tri_normal(pL,  pU,  c);  sx+=n.x; sy+=n.y; sz+=n.z; } // t2 cell(i-1,j-1)

    float nn = sqrtf(sx*sx + sy*sy + sz*sz);
    float inv = 1.0f / fmaxf(nn, 1e-8f);
    // signs per cube face: [-1, 1, 1, -1, -1, 1]
    float sgn = ((f == 1) || (f == 2) || (f == 5)) ? 1.0f : -1.0f;
    inv *= sgn;

    int o = idx * 3;
    vn[o]   = sx * inv;
    vn[o+1] = sy * inv;
    vn[o+2] = sz * inv;
}

extern "C" void kernel_launch(void* const* d_in, const int* in_sizes, int n_in,
                              void* d_out, int out_size, void* d_ws, size_t ws_size,
                              hipStream_t stream) {
    const float* radii  = (const float*)d_in[0];
    const float* angles = (const float*)d_in[1];
    const int*   faces  = (const int*)d_in[2];

    float* out_vert  = (float*)d_out;                           // [0, 18874368)
    float* out_faces = (float*)d_out + VERT_ELEMS;              // [18874368, 56549412)
    float* out_vn    = (float*)d_out + VERT_ELEMS + FACE_ELEMS; // [56549412, 75423780)

    dim3 blk(256);
    dim3 grd_v((NPTS + 255) / 256);
    dim3 grd_f((FACE_VEC4 + 255) / 256);

    vert_kernel<<<grd_v, blk, 0, stream>>>(radii, angles, out_vert);
    faces_kernel<<<grd_f, blk, 0, stream>>>(faces, out_faces);
    vn_kernel<<<grd_v, blk, 0, stream>>>(out_vert, out_vn);
}